// Round 2
// baseline (92.429 us; speedup 1.0000x reference)
//
#include <hip/hip_runtime.h>
#include <cstdint>
#include <cstddef>

typedef _Float16 f16;
typedef f16 f16x8 __attribute__((ext_vector_type(8)));
typedef f16 f16x4 __attribute__((ext_vector_type(4)));
typedef float f32x4 __attribute__((ext_vector_type(4)));

constexpr int NS = 2048;     // sites
constexpr int NB = 65536;    // bonds
// d_in order: sites, bonds, states, indices1, W1, b1, W2, b2, W3, b3 (all f32, idx int32)

// ---------------- CSR build ----------------
__global__ void count_kernel(const int* __restrict__ idx, int* __restrict__ counts) {
    int i = blockIdx.x * 256 + threadIdx.x;   // grid exactly 65536
    atomicAdd(&counts[idx[i]], 1);
}

__global__ void scan_kernel(const int* __restrict__ counts, int* __restrict__ offsets) {
    int l = threadIdx.x;            // 64 lanes, each owns 32 contiguous sites
    int c[32]; int run = 0;
    #pragma unroll
    for (int i = 0; i < 32; ++i) { c[i] = run; run += counts[l * 32 + i]; }
    int incl = run;
    #pragma unroll
    for (int d = 1; d < 64; d <<= 1) { int v = __shfl_up(incl, d); if (l >= d) incl += v; }
    int excl = incl - run;
    #pragma unroll
    for (int i = 0; i < 32; ++i) offsets[l * 32 + i] = excl + c[i];
}

__global__ void fill_kernel(const int* __restrict__ idx, const int* __restrict__ offsets,
                            int* __restrict__ cursor, int* __restrict__ bucket) {
    int i = blockIdx.x * 256 + threadIdx.x;   // grid exactly 65536
    int s = idx[i];
    int pos = atomicAdd(&cursor[s], 1);
    bucket[offsets[s] + pos] = i;
}

// ---------------- scatter-mean as gather ----------------
// block = one site; 256 threads = 16 batches x 16 float4 chunks. Each thread
// owns its (batch, 16B-chunk) accumulator; no cross-lane reduction needed.
__global__ __launch_bounds__(256) void pool_kernel(const float* __restrict__ bonds,
                                                   const int* __restrict__ counts,
                                                   const int* __restrict__ offsets,
                                                   const int* __restrict__ bucket,
                                                   float* __restrict__ pool) {
    int s = blockIdx.x;
    int t = threadIdx.x;
    int b = t >> 4, f4 = t & 15;
    int cnt = counts[s], start = offsets[s];
    f32x4 acc = {0.f, 0.f, 0.f, 0.f};
    const f32x4* base = reinterpret_cast<const f32x4*>(bonds) + (size_t)b * NB * 16;
    int i = 0;
    for (; i + 4 <= cnt; i += 4) {
        int id0 = bucket[start + i + 0];
        int id1 = bucket[start + i + 1];
        int id2 = bucket[start + i + 2];
        int id3 = bucket[start + i + 3];
        f32x4 v0 = base[(size_t)id0 * 16 + f4];
        f32x4 v1 = base[(size_t)id1 * 16 + f4];
        f32x4 v2 = base[(size_t)id2 * 16 + f4];
        f32x4 v3 = base[(size_t)id3 * 16 + f4];
        acc += v0; acc += v1; acc += v2; acc += v3;
    }
    for (; i < cnt; ++i) {
        int id = bucket[start + i];
        acc += base[(size_t)id * 16 + f4];
    }
    float inv = 1.0f / (float)(cnt > 1 ? cnt : 1);
    acc *= inv;
    reinterpret_cast<f32x4*>(pool)[((size_t)b * NS + s) * 16 + f4] = acc;
}

// ---------------- weight pre-pack (f32 -> f16 MFMA B-fragment order) ----------------
// tile (kt,nt): lane l holds W[kt*32 + (l>>4)*8 + j][nt*16 + (l&15)], j=0..7 contiguous.
// W1: 6x16 tiles, W2: 8x16, W3: 8x4  -> 256 tiles total, 64 lanes each.
__global__ void pack_kernel(const float* __restrict__ W1, const float* __restrict__ W2,
                            const float* __restrict__ W3, f16* __restrict__ pw1,
                            f16* __restrict__ pw2, f16* __restrict__ pw3) {
    int t = blockIdx.x * 256 + threadIdx.x;   // grid exactly 16384
    int tt = t >> 6, l = t & 63;
    const float* W; f16* dst; int N, tloc, kt, nt;
    if (tt < 96)       { W = W1; dst = pw1; N = 256; tloc = tt;       kt = tloc >> 4; nt = tloc & 15; }
    else if (tt < 224) { W = W2; dst = pw2; N = 256; tloc = tt - 96;  kt = tloc >> 4; nt = tloc & 15; }
    else               { W = W3; dst = pw3; N = 64;  tloc = tt - 224; kt = tloc >> 2; nt = tloc & 3;  }
    int kbase = kt * 32 + (l >> 4) * 8;
    int n = nt * 16 + (l & 15);
    f16x8 o;
    #pragma unroll
    for (int j = 0; j < 8; ++j) o[j] = (f16)W[(size_t)(kbase + j) * N + n];
    *reinterpret_cast<f16x8*>(&dst[(size_t)(tloc * 64 + l) * 8]) = o;
}

// ---------------- fused 3-layer MLP (f16 MFMA, f32 accum/IO) ----------------
// block: 32 rows (one batch), 4 waves. GEMM1/2: wave w owns cols [64w,64w+64).
// GEMM3 (N=64): wave w owns cols [16w,16w+16).
__global__ __launch_bounds__(256, 4) void mlp_kernel(
    const float* __restrict__ pool, const float* __restrict__ sites, const float* __restrict__ states,
    const float* __restrict__ b1, const float* __restrict__ b2, const float* __restrict__ b3,
    const f16x8* __restrict__ pw1, const f16x8* __restrict__ pw2, const f16x8* __restrict__ pw3,
    float* __restrict__ out) {
    constexpr int STR = 280;                 // f16 row stride: 560B rows, 16B-aligned, 2-way-max banks
    __shared__ f16 bufA[32 * STR];           // V (192 cols), later h2 (256 cols)
    __shared__ f16 bufB[32 * STR];           // h1 (256 cols)
    int t = threadIdx.x;
    int w = t >> 6, lane = t & 63;
    int arow = lane & 15, ag = lane >> 4;
    int m0 = blockIdx.x * 32;
    int b = m0 >> 11;

    // stage V = [pool | sites | states] as f16
    {
        const float* srcs[3] = { pool + (size_t)m0 * 64,
                                 sites + (size_t)m0 * 64,
                                 states + (size_t)b * 64 };
        #pragma unroll
        for (int seg = 0; seg < 3; ++seg) {
            #pragma unroll
            for (int p = 0; p < 2; ++p) {
                int i = p * 256 + t;
                int row = i >> 4, c4 = i & 15;
                const float* sp = srcs[seg] + (seg == 2 ? (size_t)0 : (size_t)row * 64) + c4 * 4;
                f32x4 v = *reinterpret_cast<const f32x4*>(sp);
                f16x4 h = { (f16)v[0], (f16)v[1], (f16)v[2], (f16)v[3] };
                *reinterpret_cast<f16x4*>(&bufA[row * STR + seg * 64 + c4 * 4]) = h;
            }
        }
    }
    __syncthreads();

    // ---- GEMM1: h1 = relu(V @ W1 + b1), K=192 ----
    {
        f32x4 acc[2][4];
        #pragma unroll
        for (int ni = 0; ni < 4; ++ni) {
            float bv = b1[w * 64 + ni * 16 + arow];
            acc[0][ni] = f32x4{bv, bv, bv, bv};
            acc[1][ni] = f32x4{bv, bv, bv, bv};
        }
        #pragma unroll
        for (int kt = 0; kt < 6; ++kt) {
            f16x8 af[2], bfr[4];
            #pragma unroll
            for (int mi = 0; mi < 2; ++mi)
                af[mi] = *reinterpret_cast<const f16x8*>(&bufA[(mi * 16 + arow) * STR + kt * 32 + ag * 8]);
            #pragma unroll
            for (int ni = 0; ni < 4; ++ni) bfr[ni] = pw1[(kt * 16 + w * 4 + ni) * 64 + lane];
            #pragma unroll
            for (int mi = 0; mi < 2; ++mi)
                #pragma unroll
                for (int ni = 0; ni < 4; ++ni)
                    acc[mi][ni] = __builtin_amdgcn_mfma_f32_16x16x32_f16(af[mi], bfr[ni], acc[mi][ni], 0, 0, 0);
        }
        #pragma unroll
        for (int mi = 0; mi < 2; ++mi)
            #pragma unroll
            for (int ni = 0; ni < 4; ++ni)
                #pragma unroll
                for (int j = 0; j < 4; ++j) {
                    float x = acc[mi][ni][j]; x = x > 0.f ? x : 0.f;
                    bufB[(mi * 16 + ag * 4 + j) * STR + w * 64 + ni * 16 + arow] = (f16)x;
                }
    }
    __syncthreads();

    // ---- GEMM2: h2 = relu(h1 @ W2 + b2), K=256 ----
    {
        f32x4 acc[2][4];
        #pragma unroll
        for (int ni = 0; ni < 4; ++ni) {
            float bv = b2[w * 64 + ni * 16 + arow];
            acc[0][ni] = f32x4{bv, bv, bv, bv};
            acc[1][ni] = f32x4{bv, bv, bv, bv};
        }
        #pragma unroll
        for (int kt = 0; kt < 8; ++kt) {
            f16x8 af[2], bfr[4];
            #pragma unroll
            for (int mi = 0; mi < 2; ++mi)
                af[mi] = *reinterpret_cast<const f16x8*>(&bufB[(mi * 16 + arow) * STR + kt * 32 + ag * 8]);
            #pragma unroll
            for (int ni = 0; ni < 4; ++ni) bfr[ni] = pw2[(kt * 16 + w * 4 + ni) * 64 + lane];
            #pragma unroll
            for (int mi = 0; mi < 2; ++mi)
                #pragma unroll
                for (int ni = 0; ni < 4; ++ni)
                    acc[mi][ni] = __builtin_amdgcn_mfma_f32_16x16x32_f16(af[mi], bfr[ni], acc[mi][ni], 0, 0, 0);
        }
        #pragma unroll
        for (int mi = 0; mi < 2; ++mi)
            #pragma unroll
            for (int ni = 0; ni < 4; ++ni)
                #pragma unroll
                for (int j = 0; j < 4; ++j) {
                    float x = acc[mi][ni][j]; x = x > 0.f ? x : 0.f;
                    bufA[(mi * 16 + ag * 4 + j) * STR + w * 64 + ni * 16 + arow] = (f16)x;
                }
    }
    __syncthreads();

    // ---- GEMM3: out = relu(h2 @ W3 + b3), K=256, N=64 ----
    {
        f32x4 acc[2];
        float bv = b3[w * 16 + arow];
        acc[0] = f32x4{bv, bv, bv, bv};
        acc[1] = f32x4{bv, bv, bv, bv};
        #pragma unroll
        for (int kt = 0; kt < 8; ++kt) {
            f16x8 bfr = pw3[(kt * 4 + w) * 64 + lane];
            #pragma unroll
            for (int mi = 0; mi < 2; ++mi) {
                f16x8 af = *reinterpret_cast<const f16x8*>(&bufA[(mi * 16 + arow) * STR + kt * 32 + ag * 8]);
                acc[mi] = __builtin_amdgcn_mfma_f32_16x16x32_f16(af, bfr, acc[mi], 0, 0, 0);
            }
        }
        #pragma unroll
        for (int mi = 0; mi < 2; ++mi)
            #pragma unroll
            for (int j = 0; j < 4; ++j) {
                float x = acc[mi][j]; x = x > 0.f ? x : 0.f;
                out[(size_t)(m0 + mi * 16 + ag * 4 + j) * 64 + w * 16 + arow] = x;
            }
    }
}

extern "C" void kernel_launch(void* const* d_in, const int* in_sizes, int n_in,
                              void* d_out, int out_size, void* d_ws, size_t ws_size,
                              hipStream_t stream) {
    (void)in_sizes; (void)n_in; (void)out_size; (void)ws_size;
    const float* sites  = (const float*)d_in[0];
    const float* bonds  = (const float*)d_in[1];
    const float* states = (const float*)d_in[2];
    const int*   idx    = (const int*)d_in[3];
    const float* W1 = (const float*)d_in[4];
    const float* b1 = (const float*)d_in[5];
    const float* W2 = (const float*)d_in[6];
    const float* b2 = (const float*)d_in[7];
    const float* W3 = (const float*)d_in[8];
    const float* b3 = (const float*)d_in[9];
    float* out = (float*)d_out;

    char* ws = (char*)d_ws;
    int* counts  = (int*)(ws + 0);          // 2048 * 4
    int* cursor  = (int*)(ws + 8192);       // 2048 * 4
    int* offsets = (int*)(ws + 16384);      // 2048 * 4
    int* bucket  = (int*)(ws + 24576);      // 65536 * 4 = 256 KiB
    float* pool  = (float*)(ws + 24576 + 262144);             // 16*2048*64*4 = 8 MiB
    f16* pw1     = (f16*)(ws + 24576 + 262144 + 8388608);     // 96*512 f16
    f16* pw2     = pw1 + 96 * 512;                             // 128*512 f16
    f16* pw3     = pw2 + 128 * 512;                            // 32*512 f16

    hipMemsetAsync(counts, 0, 16384, stream);   // zeros counts + cursor
    pack_kernel<<<64, 256, 0, stream>>>(W1, W2, W3, pw1, pw2, pw3);
    count_kernel<<<256, 256, 0, stream>>>(idx, counts);
    scan_kernel<<<1, 64, 0, stream>>>(counts, offsets);
    fill_kernel<<<256, 256, 0, stream>>>(idx, offsets, cursor, bucket);
    pool_kernel<<<2048, 256, 0, stream>>>(bonds, counts, offsets, bucket, pool);
    mlp_kernel<<<1024, 256, 0, stream>>>(pool, sites, states, b1, b2, b3,
                                         (const f16x8*)pw1, (const f16x8*)pw2, (const f16x8*)pw3, out);
}

// Round 3
// 86.777 us; speedup vs baseline: 1.0651x; 1.0651x over previous
//
#include <hip/hip_runtime.h>
#include <cstdint>
#include <cstddef>

typedef _Float16 f16;
typedef f16 f16x8 __attribute__((ext_vector_type(8)));
typedef f16 f16x4 __attribute__((ext_vector_type(4)));
typedef float f32x4 __attribute__((ext_vector_type(4)));

constexpr int NS = 2048;     // sites
constexpr int NB = 65536;    // bonds
// d_in order: sites, bonds, states, indices1, W1, b1, W2, b2, W3, b3 (all f32, idx int32)

// ---------------- pack (blocks 0..63) + count (blocks 64..319) ----------------
// pack: tile (kt,nt): lane l holds W[kt*32 + (l>>4)*8 + j][nt*16 + (l&15)], j=0..7.
// W1: 6x16 tiles, W2: 8x16, W3: 8x4 -> 256 tiles, 64 lanes each.
__global__ void pack_count_kernel(const float* __restrict__ W1, const float* __restrict__ W2,
                                  const float* __restrict__ W3, f16* __restrict__ pw1,
                                  f16* __restrict__ pw2, f16* __restrict__ pw3,
                                  const int* __restrict__ idx, int* __restrict__ counts) {
    if (blockIdx.x < 64) {
        int t = blockIdx.x * 256 + threadIdx.x;   // 16384 threads
        int tt = t >> 6, l = t & 63;
        const float* W; f16* dst; int N, tloc, kt, nt;
        if (tt < 96)       { W = W1; dst = pw1; N = 256; tloc = tt;       kt = tloc >> 4; nt = tloc & 15; }
        else if (tt < 224) { W = W2; dst = pw2; N = 256; tloc = tt - 96;  kt = tloc >> 4; nt = tloc & 15; }
        else               { W = W3; dst = pw3; N = 64;  tloc = tt - 224; kt = tloc >> 2; nt = tloc & 3;  }
        int kbase = kt * 32 + (l >> 4) * 8;
        int n = nt * 16 + (l & 15);
        f16x8 o;
        #pragma unroll
        for (int j = 0; j < 8; ++j) o[j] = (f16)W[(size_t)(kbase + j) * N + n];
        *reinterpret_cast<f16x8*>(&dst[(size_t)(tloc * 64 + l) * 8]) = o;
    } else {
        int i = (blockIdx.x - 64) * 256 + threadIdx.x;   // 65536 threads
        atomicAdd(&counts[idx[i]], 1);
    }
}

__global__ void scan_kernel(const int* __restrict__ counts, int* __restrict__ offsets) {
    int l = threadIdx.x;            // 64 lanes, each owns 32 contiguous sites
    int c[32]; int run = 0;
    #pragma unroll
    for (int i = 0; i < 32; ++i) { c[i] = run; run += counts[l * 32 + i]; }
    int incl = run;
    #pragma unroll
    for (int d = 1; d < 64; d <<= 1) { int v = __shfl_up(incl, d); if (l >= d) incl += v; }
    int excl = incl - run;
    #pragma unroll
    for (int i = 0; i < 32; ++i) offsets[l * 32 + i] = excl + c[i];
}

__global__ void fill_kernel(const int* __restrict__ idx, const int* __restrict__ offsets,
                            int* __restrict__ cursor, int* __restrict__ bucket) {
    int i = blockIdx.x * 256 + threadIdx.x;   // grid exactly 65536
    int s = idx[i];
    int pos = atomicAdd(&cursor[s], 1);
    bucket[offsets[s] + pos] = i;
}

// ---------------- fused gather-pool + 3-layer MLP ----------------
// block = (batch b, 32-site chunk). 256 threads, 4 waves.
// Phase 0: gather-mean bonds for 32 sites into LDS V cols 0..63 (f32 acc -> f16),
//          stage sites (64..127) and states (128..191).
// GEMM1/2: wave w owns cols [64w, 64w+64). GEMM3 (N=64): wave w owns [16w,16w+16).
__global__ __launch_bounds__(256, 4) void fused_kernel(
    const float* __restrict__ bonds, const float* __restrict__ sites, const float* __restrict__ states,
    const int* __restrict__ counts, const int* __restrict__ offsets, const int* __restrict__ bucket,
    const float* __restrict__ b1, const float* __restrict__ b2, const float* __restrict__ b3,
    const f16x8* __restrict__ pw1, const f16x8* __restrict__ pw2, const f16x8* __restrict__ pw3,
    float* __restrict__ out) {
    constexpr int STR = 280;                 // f16 row stride: 560B rows, 16B-aligned
    __shared__ f16 bufA[32 * STR];           // V (192 cols), later h2 (256 cols)
    __shared__ f16 bufB[32 * STR];           // h1 (256 cols)
    int t = threadIdx.x;
    int w = t >> 6, lane = t & 63;
    int arow = lane & 15, ag = lane >> 4;
    int blk = blockIdx.x;
    int b = blk >> 6;                        // 64 chunks per batch
    int s0 = (blk & 63) * 32;                // first site of chunk
    int m0 = b * NS + s0;                    // first output row

    // ---- phase 0a: gather-mean over bonds (cols 0..63) ----
    {
        int slot = t >> 4, f4 = t & 15;      // 16 site-slots x 16 float4-chunks
        const f32x4* base = reinterpret_cast<const f32x4*>(bonds) + (size_t)b * NB * 16;
        #pragma unroll
        for (int sg = 0; sg < 2; ++sg) {
            int srow = sg * 16 + slot;
            int s = s0 + srow;
            int cnt = counts[s], start = offsets[s];
            f32x4 acc = {0.f, 0.f, 0.f, 0.f};
            int i = 0;
            for (; i + 4 <= cnt; i += 4) {
                int id0 = bucket[start + i + 0];
                int id1 = bucket[start + i + 1];
                int id2 = bucket[start + i + 2];
                int id3 = bucket[start + i + 3];
                f32x4 v0 = base[(size_t)id0 * 16 + f4];
                f32x4 v1 = base[(size_t)id1 * 16 + f4];
                f32x4 v2 = base[(size_t)id2 * 16 + f4];
                f32x4 v3 = base[(size_t)id3 * 16 + f4];
                acc += v0; acc += v1; acc += v2; acc += v3;
            }
            for (; i < cnt; ++i) {
                int id = bucket[start + i];
                acc += base[(size_t)id * 16 + f4];
            }
            float inv = 1.0f / (float)(cnt > 1 ? cnt : 1);
            acc *= inv;
            f16x4 h = { (f16)acc[0], (f16)acc[1], (f16)acc[2], (f16)acc[3] };
            *reinterpret_cast<f16x4*>(&bufA[srow * STR + f4 * 4]) = h;
        }
    }
    // ---- phase 0b: stage sites (cols 64..127) and states (cols 128..191) ----
    {
        #pragma unroll
        for (int p = 0; p < 2; ++p) {
            int i = p * 256 + t;             // 512: 32 rows x 16 chunks
            int row = i >> 4, c4 = i & 15;
            f32x4 v = *reinterpret_cast<const f32x4*>(sites + (size_t)(m0 + row) * 64 + c4 * 4);
            f16x4 h = { (f16)v[0], (f16)v[1], (f16)v[2], (f16)v[3] };
            *reinterpret_cast<f16x4*>(&bufA[row * STR + 64 + c4 * 4]) = h;
        }
        f32x4 v = *reinterpret_cast<const f32x4*>(states + (size_t)b * 64 + (t & 15) * 4);
        f16x4 h = { (f16)v[0], (f16)v[1], (f16)v[2], (f16)v[3] };
        #pragma unroll
        for (int p = 0; p < 2; ++p) {
            int row = p * 16 + (t >> 4), c4 = t & 15;
            *reinterpret_cast<f16x4*>(&bufA[row * STR + 128 + c4 * 4]) = h;
        }
    }
    __syncthreads();

    // ---- GEMM1: h1 = relu(V @ W1 + b1), K=192 ----
    {
        f32x4 acc[2][4];
        #pragma unroll
        for (int ni = 0; ni < 4; ++ni) {
            float bv = b1[w * 64 + ni * 16 + arow];
            acc[0][ni] = f32x4{bv, bv, bv, bv};
            acc[1][ni] = f32x4{bv, bv, bv, bv};
        }
        #pragma unroll
        for (int kt = 0; kt < 6; ++kt) {
            f16x8 af[2], bfr[4];
            #pragma unroll
            for (int mi = 0; mi < 2; ++mi)
                af[mi] = *reinterpret_cast<const f16x8*>(&bufA[(mi * 16 + arow) * STR + kt * 32 + ag * 8]);
            #pragma unroll
            for (int ni = 0; ni < 4; ++ni) bfr[ni] = pw1[(kt * 16 + w * 4 + ni) * 64 + lane];
            #pragma unroll
            for (int mi = 0; mi < 2; ++mi)
                #pragma unroll
                for (int ni = 0; ni < 4; ++ni)
                    acc[mi][ni] = __builtin_amdgcn_mfma_f32_16x16x32_f16(af[mi], bfr[ni], acc[mi][ni], 0, 0, 0);
        }
        #pragma unroll
        for (int mi = 0; mi < 2; ++mi)
            #pragma unroll
            for (int ni = 0; ni < 4; ++ni)
                #pragma unroll
                for (int j = 0; j < 4; ++j) {
                    float x = acc[mi][ni][j]; x = x > 0.f ? x : 0.f;
                    bufB[(mi * 16 + ag * 4 + j) * STR + w * 64 + ni * 16 + arow] = (f16)x;
                }
    }
    __syncthreads();

    // ---- GEMM2: h2 = relu(h1 @ W2 + b2), K=256 ----
    {
        f32x4 acc[2][4];
        #pragma unroll
        for (int ni = 0; ni < 4; ++ni) {
            float bv = b2[w * 64 + ni * 16 + arow];
            acc[0][ni] = f32x4{bv, bv, bv, bv};
            acc[1][ni] = f32x4{bv, bv, bv, bv};
        }
        #pragma unroll
        for (int kt = 0; kt < 8; ++kt) {
            f16x8 af[2], bfr[4];
            #pragma unroll
            for (int mi = 0; mi < 2; ++mi)
                af[mi] = *reinterpret_cast<const f16x8*>(&bufB[(mi * 16 + arow) * STR + kt * 32 + ag * 8]);
            #pragma unroll
            for (int ni = 0; ni < 4; ++ni) bfr[ni] = pw2[(kt * 16 + w * 4 + ni) * 64 + lane];
            #pragma unroll
            for (int mi = 0; mi < 2; ++mi)
                #pragma unroll
                for (int ni = 0; ni < 4; ++ni)
                    acc[mi][ni] = __builtin_amdgcn_mfma_f32_16x16x32_f16(af[mi], bfr[ni], acc[mi][ni], 0, 0, 0);
        }
        #pragma unroll
        for (int mi = 0; mi < 2; ++mi)
            #pragma unroll
            for (int ni = 0; ni < 4; ++ni)
                #pragma unroll
                for (int j = 0; j < 4; ++j) {
                    float x = acc[mi][ni][j]; x = x > 0.f ? x : 0.f;
                    bufA[(mi * 16 + ag * 4 + j) * STR + w * 64 + ni * 16 + arow] = (f16)x;
                }
    }
    __syncthreads();

    // ---- GEMM3: out = relu(h2 @ W3 + b3), K=256, N=64 ----
    {
        f32x4 acc[2];
        float bv = b3[w * 16 + arow];
        acc[0] = f32x4{bv, bv, bv, bv};
        acc[1] = f32x4{bv, bv, bv, bv};
        #pragma unroll
        for (int kt = 0; kt < 8; ++kt) {
            f16x8 bfr = pw3[(kt * 4 + w) * 64 + lane];
            #pragma unroll
            for (int mi = 0; mi < 2; ++mi) {
                f16x8 af = *reinterpret_cast<const f16x8*>(&bufA[(mi * 16 + arow) * STR + kt * 32 + ag * 8]);
                acc[mi] = __builtin_amdgcn_mfma_f32_16x16x32_f16(af, bfr, acc[mi], 0, 0, 0);
            }
        }
        #pragma unroll
        for (int mi = 0; mi < 2; ++mi)
            #pragma unroll
            for (int j = 0; j < 4; ++j) {
                float x = acc[mi][j]; x = x > 0.f ? x : 0.f;
                out[(size_t)(m0 + mi * 16 + ag * 4 + j) * 64 + w * 16 + arow] = x;
            }
    }
}

extern "C" void kernel_launch(void* const* d_in, const int* in_sizes, int n_in,
                              void* d_out, int out_size, void* d_ws, size_t ws_size,
                              hipStream_t stream) {
    (void)in_sizes; (void)n_in; (void)out_size; (void)ws_size;
    const float* sites  = (const float*)d_in[0];
    const float* bonds  = (const float*)d_in[1];
    const float* states = (const float*)d_in[2];
    const int*   idx    = (const int*)d_in[3];
    const float* W1 = (const float*)d_in[4];
    const float* b1 = (const float*)d_in[5];
    const float* W2 = (const float*)d_in[6];
    const float* b2 = (const float*)d_in[7];
    const float* W3 = (const float*)d_in[8];
    const float* b3 = (const float*)d_in[9];
    float* out = (float*)d_out;

    char* ws = (char*)d_ws;
    int* counts  = (int*)(ws + 0);          // 2048 * 4
    int* cursor  = (int*)(ws + 8192);       // 2048 * 4
    int* offsets = (int*)(ws + 16384);      // 2048 * 4
    int* bucket  = (int*)(ws + 24576);      // 65536 * 4 = 256 KiB
    f16* pw1     = (f16*)(ws + 24576 + 262144);   // 96*512 f16
    f16* pw2     = pw1 + 96 * 512;                 // 128*512 f16
    f16* pw3     = pw2 + 128 * 512;                // 32*512 f16

    hipMemsetAsync(counts, 0, 16384, stream);   // zeros counts + cursor
    pack_count_kernel<<<320, 256, 0, stream>>>(W1, W2, W3, pw1, pw2, pw3, idx, counts);
    scan_kernel<<<1, 64, 0, stream>>>(counts, offsets);
    fill_kernel<<<256, 256, 0, stream>>>(idx, offsets, cursor, bucket);
    fused_kernel<<<1024, 256, 0, stream>>>(bonds, sites, states, counts, offsets, bucket,
                                           b1, b2, b3,
                                           (const f16x8*)pw1, (const f16x8*)pw2, (const f16x8*)pw3, out);
}

// Round 4
// 85.647 us; speedup vs baseline: 1.0792x; 1.0132x over previous
//
#include <hip/hip_runtime.h>
#include <cstdint>
#include <cstddef>

typedef _Float16 f16;
typedef f16 f16x8 __attribute__((ext_vector_type(8)));
typedef f16 f16x4 __attribute__((ext_vector_type(4)));
typedef float f32x4 __attribute__((ext_vector_type(4)));

constexpr int NS = 2048;     // sites
constexpr int NB = 65536;    // bonds
// d_in order: sites, bonds, states, indices1, W1, b1, W2, b2, W3, b3 (all f32, idx int32)

// ---------------- weight pre-pack (f32 -> f16 MFMA B-fragment order) ----------------
// tile (kt,nt): lane l holds W[kt*32 + (l>>4)*8 + j][nt*16 + (l&15)], j=0..7 contiguous.
// W1: 6x16 tiles, W2: 8x16, W3: 8x4 -> 256 tiles, 64 lanes each.
__global__ void pack_kernel(const float* __restrict__ W1, const float* __restrict__ W2,
                            const float* __restrict__ W3, f16* __restrict__ pw1,
                            f16* __restrict__ pw2, f16* __restrict__ pw3) {
    int t = blockIdx.x * 256 + threadIdx.x;   // grid exactly 16384
    int tt = t >> 6, l = t & 63;
    const float* W; f16* dst; int N, tloc, kt, nt;
    if (tt < 96)       { W = W1; dst = pw1; N = 256; tloc = tt;       kt = tloc >> 4; nt = tloc & 15; }
    else if (tt < 224) { W = W2; dst = pw2; N = 256; tloc = tt - 96;  kt = tloc >> 4; nt = tloc & 15; }
    else               { W = W3; dst = pw3; N = 64;  tloc = tt - 224; kt = tloc >> 2; nt = tloc & 3;  }
    int kbase = kt * 32 + (l >> 4) * 8;
    int n = nt * 16 + (l & 15);
    f16x8 o;
    #pragma unroll
    for (int j = 0; j < 8; ++j) o[j] = (f16)W[(size_t)(kbase + j) * N + n];
    *reinterpret_cast<f16x8*>(&dst[(size_t)(tloc * 64 + l) * 8]) = o;
}

// ---------------- fused scan + gather-pool + 3-layer MLP ----------------
// block = (batch b, 32-site chunk). 256 threads, 4 waves.
// Phase A: scan all 65536 indices (int4, L2-resident), compact bond-ids of our
//          32 sites into an LDS queue (overlaid on bufB) via LDS atomics.
// Phase B: gather-mean bond rows (random 256B HBM reads) into V cols 0..63;
//          stage sites (64..127) and states (128..191).
// GEMM1/2: wave w owns cols [64w, 64w+64). GEMM3 (N=64): wave w owns [16w,16w+16).
__global__ __launch_bounds__(256, 4) void fused_kernel(
    const float* __restrict__ bonds, const float* __restrict__ sites, const float* __restrict__ states,
    const int* __restrict__ idx,
    const float* __restrict__ b1, const float* __restrict__ b2, const float* __restrict__ b3,
    const f16x8* __restrict__ pw1, const f16x8* __restrict__ pw2, const f16x8* __restrict__ pw3,
    float* __restrict__ out) {
    constexpr int STR = 280;                 // f16 row stride: 560B rows, 16B-aligned
    __shared__ f16 bufA[32 * STR];           // V (192 cols), later h2 (256 cols)
    __shared__ f16 bufB[32 * STR];           // queue (16 KB), then h1 (256 cols)
    __shared__ int qcnt[32];
    int t = threadIdx.x;
    int w = t >> 6, lane = t & 63;
    int arow = lane & 15, ag = lane >> 4;
    int blk = blockIdx.x;
    int b = blk >> 6;                        // 64 chunks per batch
    int s0 = (blk & 63) * 32;                // first site of chunk
    int m0 = b * NS + s0;                    // first output row

    int* queue = reinterpret_cast<int*>(bufB);   // [32][128] ids, 16384 B <= 17920 B

    if (t < 32) qcnt[t] = 0;
    __syncthreads();

    // ---- phase A: scan indices, build per-site queues ----
    {
        const int4* idx4 = reinterpret_cast<const int4*>(idx);
        #pragma unroll 4
        for (int k = 0; k < 64; ++k) {
            int i4 = k * 256 + t;
            int4 v = idx4[i4];
            int base_i = i4 * 4;
            #pragma unroll
            for (int e = 0; e < 4; ++e) {
                int s = (&v.x)[e];
                unsigned d = (unsigned)(s - s0);
                if (d < 32u) {
                    int pos = atomicAdd(&qcnt[d], 1);
                    queue[d * 128 + pos] = base_i + e;
                }
            }
        }
    }
    // ---- stage sites (cols 64..127) and states (cols 128..191) ----
    {
        #pragma unroll
        for (int p = 0; p < 2; ++p) {
            int i = p * 256 + t;             // 512: 32 rows x 16 chunks
            int row = i >> 4, c4 = i & 15;
            f32x4 v = *reinterpret_cast<const f32x4*>(sites + (size_t)(m0 + row) * 64 + c4 * 4);
            f16x4 h = { (f16)v[0], (f16)v[1], (f16)v[2], (f16)v[3] };
            *reinterpret_cast<f16x4*>(&bufA[row * STR + 64 + c4 * 4]) = h;
        }
        f32x4 v = *reinterpret_cast<const f32x4*>(states + (size_t)b * 64 + (t & 15) * 4);
        f16x4 h = { (f16)v[0], (f16)v[1], (f16)v[2], (f16)v[3] };
        #pragma unroll
        for (int p = 0; p < 2; ++p) {
            int row = p * 16 + (t >> 4), c4 = t & 15;
            *reinterpret_cast<f16x4*>(&bufA[row * STR + 128 + c4 * 4]) = h;
        }
    }
    __syncthreads();

    // ---- phase B: gather-mean over bonds (cols 0..63) ----
    {
        int slot = t >> 4, f4 = t & 15;      // 16 site-slots x 16 float4-chunks
        const f32x4* base = reinterpret_cast<const f32x4*>(bonds) + (size_t)b * NB * 16;
        #pragma unroll
        for (int sg = 0; sg < 2; ++sg) {
            int srow = sg * 16 + slot;
            int cnt = qcnt[srow];
            const int* qrow = queue + srow * 128;
            f32x4 acc = {0.f, 0.f, 0.f, 0.f};
            int i = 0;
            for (; i + 8 <= cnt; i += 8) {
                int id[8];
                #pragma unroll
                for (int u = 0; u < 8; ++u) id[u] = qrow[i + u];
                f32x4 v[8];
                #pragma unroll
                for (int u = 0; u < 8; ++u) v[u] = base[(size_t)id[u] * 16 + f4];
                #pragma unroll
                for (int u = 0; u < 8; ++u) acc += v[u];
            }
            for (; i + 4 <= cnt; i += 4) {
                int id0 = qrow[i + 0], id1 = qrow[i + 1], id2 = qrow[i + 2], id3 = qrow[i + 3];
                f32x4 v0 = base[(size_t)id0 * 16 + f4];
                f32x4 v1 = base[(size_t)id1 * 16 + f4];
                f32x4 v2 = base[(size_t)id2 * 16 + f4];
                f32x4 v3 = base[(size_t)id3 * 16 + f4];
                acc += v0; acc += v1; acc += v2; acc += v3;
            }
            for (; i < cnt; ++i) acc += base[(size_t)qrow[i] * 16 + f4];
            float inv = 1.0f / (float)(cnt > 1 ? cnt : 1);
            acc *= inv;
            f16x4 h = { (f16)acc[0], (f16)acc[1], (f16)acc[2], (f16)acc[3] };
            *reinterpret_cast<f16x4*>(&bufA[srow * STR + f4 * 4]) = h;
        }
    }
    __syncthreads();

    // ---- GEMM1: h1 = relu(V @ W1 + b1), K=192 ----
    {
        f32x4 acc[2][4];
        #pragma unroll
        for (int ni = 0; ni < 4; ++ni) {
            float bv = b1[w * 64 + ni * 16 + arow];
            acc[0][ni] = f32x4{bv, bv, bv, bv};
            acc[1][ni] = f32x4{bv, bv, bv, bv};
        }
        #pragma unroll
        for (int kt = 0; kt < 6; ++kt) {
            f16x8 af[2], bfr[4];
            #pragma unroll
            for (int mi = 0; mi < 2; ++mi)
                af[mi] = *reinterpret_cast<const f16x8*>(&bufA[(mi * 16 + arow) * STR + kt * 32 + ag * 8]);
            #pragma unroll
            for (int ni = 0; ni < 4; ++ni) bfr[ni] = pw1[(kt * 16 + w * 4 + ni) * 64 + lane];
            #pragma unroll
            for (int mi = 0; mi < 2; ++mi)
                #pragma unroll
                for (int ni = 0; ni < 4; ++ni)
                    acc[mi][ni] = __builtin_amdgcn_mfma_f32_16x16x32_f16(af[mi], bfr[ni], acc[mi][ni], 0, 0, 0);
        }
        __syncthreads();   // queue fully consumed; bufB becomes h1
        #pragma unroll
        for (int mi = 0; mi < 2; ++mi)
            #pragma unroll
            for (int ni = 0; ni < 4; ++ni)
                #pragma unroll
                for (int j = 0; j < 4; ++j) {
                    float x = acc[mi][ni][j]; x = x > 0.f ? x : 0.f;
                    bufB[(mi * 16 + ag * 4 + j) * STR + w * 64 + ni * 16 + arow] = (f16)x;
                }
    }
    __syncthreads();

    // ---- GEMM2: h2 = relu(h1 @ W2 + b2), K=256 ----
    {
        f32x4 acc[2][4];
        #pragma unroll
        for (int ni = 0; ni < 4; ++ni) {
            float bv = b2[w * 64 + ni * 16 + arow];
            acc[0][ni] = f32x4{bv, bv, bv, bv};
            acc[1][ni] = f32x4{bv, bv, bv, bv};
        }
        #pragma unroll
        for (int kt = 0; kt < 8; ++kt) {
            f16x8 af[2], bfr[4];
            #pragma unroll
            for (int mi = 0; mi < 2; ++mi)
                af[mi] = *reinterpret_cast<const f16x8*>(&bufB[(mi * 16 + arow) * STR + kt * 32 + ag * 8]);
            #pragma unroll
            for (int ni = 0; ni < 4; ++ni) bfr[ni] = pw2[(kt * 16 + w * 4 + ni) * 64 + lane];
            #pragma unroll
            for (int mi = 0; mi < 2; ++mi)
                #pragma unroll
                for (int ni = 0; ni < 4; ++ni)
                    acc[mi][ni] = __builtin_amdgcn_mfma_f32_16x16x32_f16(af[mi], bfr[ni], acc[mi][ni], 0, 0, 0);
        }
        __syncthreads();
        #pragma unroll
        for (int mi = 0; mi < 2; ++mi)
            #pragma unroll
            for (int ni = 0; ni < 4; ++ni)
                #pragma unroll
                for (int j = 0; j < 4; ++j) {
                    float x = acc[mi][ni][j]; x = x > 0.f ? x : 0.f;
                    bufA[(mi * 16 + ag * 4 + j) * STR + w * 64 + ni * 16 + arow] = (f16)x;
                }
    }
    __syncthreads();

    // ---- GEMM3: out = relu(h2 @ W3 + b3), K=256, N=64 ----
    {
        f32x4 acc[2];
        float bv = b3[w * 16 + arow];
        acc[0] = f32x4{bv, bv, bv, bv};
        acc[1] = f32x4{bv, bv, bv, bv};
        #pragma unroll
        for (int kt = 0; kt < 8; ++kt) {
            f16x8 bfr = pw3[(kt * 4 + w) * 64 + lane];
            #pragma unroll
            for (int mi = 0; mi < 2; ++mi) {
                f16x8 af = *reinterpret_cast<const f16x8*>(&bufA[(mi * 16 + arow) * STR + kt * 32 + ag * 8]);
                acc[mi] = __builtin_amdgcn_mfma_f32_16x16x32_f16(af, bfr, acc[mi], 0, 0, 0);
            }
        }
        #pragma unroll
        for (int mi = 0; mi < 2; ++mi)
            #pragma unroll
            for (int j = 0; j < 4; ++j) {
                float x = acc[mi][j]; x = x > 0.f ? x : 0.f;
                out[(size_t)(m0 + mi * 16 + ag * 4 + j) * 64 + w * 16 + arow] = x;
            }
    }
}

extern "C" void kernel_launch(void* const* d_in, const int* in_sizes, int n_in,
                              void* d_out, int out_size, void* d_ws, size_t ws_size,
                              hipStream_t stream) {
    (void)in_sizes; (void)n_in; (void)out_size; (void)ws_size;
    const float* sites  = (const float*)d_in[0];
    const float* bonds  = (const float*)d_in[1];
    const float* states = (const float*)d_in[2];
    const int*   idx    = (const int*)d_in[3];
    const float* W1 = (const float*)d_in[4];
    const float* b1 = (const float*)d_in[5];
    const float* W2 = (const float*)d_in[6];
    const float* b2 = (const float*)d_in[7];
    const float* W3 = (const float*)d_in[8];
    const float* b3 = (const float*)d_in[9];
    float* out = (float*)d_out;

    char* ws = (char*)d_ws;
    f16* pw1 = (f16*)ws;              // 96*512 f16
    f16* pw2 = pw1 + 96 * 512;        // 128*512 f16
    f16* pw3 = pw2 + 128 * 512;       // 32*512 f16

    pack_kernel<<<64, 256, 0, stream>>>(W1, W2, W3, pw1, pw2, pw3);
    fused_kernel<<<1024, 256, 0, stream>>>(bonds, sites, states, idx,
                                           b1, b2, b3,
                                           (const f16x8*)pw1, (const f16x8*)pw2, (const f16x8*)pw3, out);
}